// Round 3
// baseline (370.758 us; speedup 1.0000x reference)
//
#include <hip/hip_runtime.h>

#define NB 256              // histogram bins
#define NCH 48              // B*C = 16*3
#define HW (1024*1024)      // elements per channel
#define WPC (HW / 4)        // packed words per channel = 262144
#define THREADS 256
#define BPC 64              // blocks per channel -> 3072 blocks per big kernel
#define N4 (WPC / BPC)      // packed words per block = 4096 (16 per thread)

// R3 structure: barrier-free three-dispatch pipeline.
//   K1 hist_quant : read x (192 MB) -> q packed bytes (48 MB) + ghist atomics
//   K2 lut_build  : 48 blocks, scan ghist -> lut[48][256] (48 KB, L2-resident)
//   K3 remap      : read q (48 MB) + lut -> write y (192 MB)
// Rationale (R2 post-mortem): the fused single-pass kernel's software grid
// barrier serialized the device into a read-only phase then a write-only
// phase -- read and write BW never overlapped, costing ~40 us, while fusion
// only saved the 96 MB q round-trip (~15 us). Each kernel here interleaves
// its reads and writes per-wave, so both directions of the HBM interface
// stay busy. Also removes the spin barrier / co-residency gate entirely
// (suspect for bench-vs-rocprof timing discrepancy).

__device__ __forceinline__ int quant255(float v) {
    v = fminf(fmaxf(v, 0.0f), 1.0f);
    int q = (int)(v * 255.0f);     // fp32 mul + trunc, same as jnp
    q = q < 0 ? 0 : q;
    q = q > 255 ? 255 : q;
    return q;
}

// ---------------- K1: quantize + per-block LDS hist -> global hist --------
__global__ __launch_bounds__(THREADS) void hist_quant_kernel(
    const float* __restrict__ x, unsigned int* __restrict__ ghist,
    unsigned int* __restrict__ q) {
    __shared__ unsigned int lh[4 * NB];   // one 256-bin sub-hist per wave
    const int t = threadIdx.x;
    const int w = t >> 6;
    for (int i = t; i < 4 * NB; i += THREADS) lh[i] = 0u;
    __syncthreads();

    const int ch  = blockIdx.x / BPC;
    const int blk = blockIdx.x % BPC;
    const float4* xp = (const float4*)x + (size_t)ch * WPC;
    unsigned int* qp = q + (size_t)ch * WPC;
    const int base = blk * N4;

    // 16 iterations/thread; unroll 4 so several float4 loads are in flight
    #pragma unroll 4
    for (int i = base + t; i < base + N4; i += THREADS) {
        float4 v = xp[i];
        int q0 = quant255(v.x), q1 = quant255(v.y);
        int q2 = quant255(v.z), q3 = quant255(v.w);
        atomicAdd(&lh[w * NB + q0], 1u);
        atomicAdd(&lh[w * NB + q1], 1u);
        atomicAdd(&lh[w * NB + q2], 1u);
        atomicAdd(&lh[w * NB + q3], 1u);
        qp[i] = (unsigned)q0 | ((unsigned)q1 << 8)
              | ((unsigned)q2 << 16) | ((unsigned)q3 << 24);
    }
    __syncthreads();
    unsigned int s = lh[t] + lh[NB + t] + lh[2 * NB + t] + lh[3 * NB + t];
    if (s) atomicAdd(&ghist[ch * NB + t], s);
}

// ---------------- K2: per-channel CDF scan -> normalized LUT --------------
__global__ __launch_bounds__(THREADS) void lut_build_kernel(
    const unsigned int* __restrict__ ghist, float* __restrict__ lutg) {
    __shared__ float sbuf[NB];
    const int t  = threadIdx.x;
    const int ch = blockIdx.x;
    sbuf[t] = (float)ghist[ch * NB + t];   // ints < 2^24 -> exact fp32
    __syncthreads();
    for (int off = 1; off < NB; off <<= 1) {
        float add = (t >= off) ? sbuf[t - off] : 0.0f;
        __syncthreads();
        sbuf[t] += add;
        __syncthreads();
    }
    float total = sbuf[NB - 1];
    lutg[ch * NB + t] = sbuf[t] / fmaxf(total, 1.0f);
}

// ---------------- K3: remap packed q through LUT -> y ---------------------
__global__ __launch_bounds__(THREADS) void remap_kernel(
    const unsigned int* __restrict__ q, const float* __restrict__ lutg,
    float* __restrict__ y) {
    __shared__ float lut[NB];
    const int t   = threadIdx.x;
    const int ch  = blockIdx.x / BPC;
    const int blk = blockIdx.x % BPC;

    lut[t] = lutg[ch * NB + t];            // THREADS == NB: one load each
    __syncthreads();

    const unsigned int* qp = q + (size_t)ch * WPC;
    float4*             yp = (float4*)y + (size_t)ch * WPC;
    const int base = blk * N4;

    // 4 B packed read + 16 B float4 write per thread-iteration (both
    // lane-contiguous); unroll for outstanding loads
    #pragma unroll 4
    for (int i = base + t; i < base + N4; i += THREADS) {
        unsigned p = qp[i];
        yp[i] = make_float4(lut[p & 255], lut[(p >> 8) & 255],
                            lut[(p >> 16) & 255], lut[p >> 24]);
    }
}

extern "C" void kernel_launch(void* const* d_in, const int* in_sizes, int n_in,
                              void* d_out, int out_size, void* d_ws, size_t ws_size,
                              hipStream_t stream) {
    const float* x = (const float*)d_in[0];
    float* y = (float*)d_out;

    unsigned int* ghist = (unsigned int*)d_ws;                        // 48 KB
    float*        lutg  = (float*)((char*)d_ws + 64 * 1024);          // 48 KB
    unsigned int* q     = (unsigned int*)((char*)d_ws + 256 * 1024);  // 48 MB

    // zero ghist (ws is 0xAA-poisoned before every launch)
    hipMemsetAsync(d_ws, 0, 48 * 1024, stream);

    hist_quant_kernel<<<NCH * BPC, THREADS, 0, stream>>>(x, ghist, q);
    lut_build_kernel <<<NCH,       THREADS, 0, stream>>>(ghist, lutg);
    remap_kernel     <<<NCH * BPC, THREADS, 0, stream>>>(q, lutg, y);
}